// Round 1
// 949.929 us; speedup vs baseline: 1.0893x; 1.0893x over previous
//
#include <hip/hip_runtime.h>
#include <cstdint>
#include <type_traits>

typedef short bf16x8 __attribute__((ext_vector_type(8)));
typedef float f32x4 __attribute__((ext_vector_type(4)));

__device__ __forceinline__ ushort f2bf(float f) {
  union { float f; uint32_t u; } v; v.f = f;
  return (ushort)((v.u + 0x7fffu + ((v.u >> 16) & 1u)) >> 16);
}
__device__ __forceinline__ float bf2f(ushort u) {
  union { uint32_t u; float f; } v; v.u = ((uint32_t)u) << 16;
  return v.f;
}
__device__ __forceinline__ uint32_t pkbf(float x, float y) {
  uint32_t ux = (__float_as_uint(x) + 0x8000u) >> 16;
  uint32_t uy = (__float_as_uint(y) + 0x8000u) & 0xffff0000u;
  return ux | uy;
}

// async global->LDS, 16B per lane; LDS base must be wave-uniform,
// HW writes lane l at base + l*16.
__device__ __forceinline__ void gld16(const void* g, void* l) {
  __builtin_amdgcn_global_load_lds(
      (__attribute__((address_space(1))) void*)(g),
      (__attribute__((address_space(3))) void*)(l), 16, 0, 0);
}

__device__ __forceinline__ uint4 ld8(const ushort* p) { return *(const uint4*)p; }
__device__ __forceinline__ uint4 ld8(const float* p) {
  float4 a = *(const float4*)p;
  float4 b = *(const float4*)(p + 4);
  uint4 r;
  r.x = pkbf(a.x, a.y); r.y = pkbf(a.z, a.w);
  r.z = pkbf(b.x, b.y); r.w = pkbf(b.z, b.w);
  return r;
}

// ---------------------------------------------------------------------------
// fp32 -> bf16 bulk convert: 8 elements/thread
// ---------------------------------------------------------------------------
__global__ __launch_bounds__(256) void cvt_bf16(
    const float* __restrict__ src, ushort* __restrict__ dst, int n8)
{
  int i = blockIdx.x * 256 + threadIdx.x;
  if (i >= n8) return;
  const float4* s = (const float4*)src;
  float4 a = s[2 * i], b = s[2 * i + 1];
  uint4 r;
  r.x = pkbf(a.x, a.y); r.y = pkbf(a.z, a.w);
  r.z = pkbf(b.x, b.y); r.w = pkbf(b.z, b.w);
  ((uint4*)dst)[i] = r;
}

// ===========================================================================
// 256x256 8-phase QKV GEMM (m201-style template, plain HIP).
//   512 threads = 8 waves (2M x 4N), BK=64, 128 KiB LDS,
//   counted vmcnt(6), setprio around MFMA clusters, subtiled conflict-free
//   LDS layout achieved by pre-permuting the global_load_lds SOURCE address.
// Grid: 384 blocks flat. xt<32: C = hidden*[Wk;Wv]^T (route K / V^T);
//                        xt>=32: C = latents*Wq^T (route Q).
// ===========================================================================

#define BARw() __builtin_amdgcn_s_barrier()
#define LGKMW() do { asm volatile("s_waitcnt lgkmcnt(0)" ::: "memory"); \
                     __builtin_amdgcn_sched_barrier(0); } while (0)
#define VM6() asm volatile("s_waitcnt vmcnt(6)" ::: "memory")
#define VM0() asm volatile("s_waitcnt vmcnt(0)" ::: "memory")

// Stage one 128x64 half-tile (16 KiB) into LDS at `lds` (subtile layout).
// Linear LDS write order == [si=sr*2+sc][local_r][local_c] subtile layout:
//   lane l of (q,wave): si = q*8+wave, local_r = l>>2, local_c = (l&3)*8.
__device__ __forceinline__ void stage_half8(
    const ushort* __restrict__ G, int row0, int col0,
    ushort* lds, int wave, int r4, int c8)
{
#pragma unroll
  for (int q = 0; q < 2; ++q) {
    const int si = q * 8 + wave;
    const ushort* g = G + (size_t)(row0 + (si >> 1) * 16 + r4) * 4096
                        + (col0 + (si & 1) * 32 + c8);
    gld16(g, lds + si * 512);
  }
}

// A-fragment reads: 4 m-frags x 2 k-steps from one half (8 x ds_read_b128).
__device__ __forceinline__ void read_a8(const ushort* base, int wm, int l16,
                                        int quad, bf16x8 (&a)[4][2])
{
#pragma unroll
  for (int f = 0; f < 4; ++f)
#pragma unroll
    for (int ks = 0; ks < 2; ++ks)
      a[f][ks] = *(const bf16x8*)(base + ((wm * 4 + f) * 2 + ks) * 512
                                       + l16 * 32 + quad * 8);
}

// B-fragment reads: 2 n-frags x 2 k-steps from one half (4 x ds_read_b128).
__device__ __forceinline__ void read_b8(const ushort* base, int wn, int l16,
                                        int quad, bf16x8 (&b)[2][2])
{
#pragma unroll
  for (int f = 0; f < 2; ++f)
#pragma unroll
    for (int ks = 0; ks < 2; ++ks)
      b[f][ks] = *(const bf16x8*)(base + ((wn * 2 + f) * 2 + ks) * 512
                                       + l16 * 32 + quad * 8);
}

// One C-quadrant x K=64: 16 MFMA, setprio-wrapped. MH/NH compile-time so all
// acc indices are static (no scratch).
template <int MH, int NH>
__device__ __forceinline__ void mfma_quad(const bf16x8 (&a)[4][2],
                                          const bf16x8 (&b)[2][2],
                                          f32x4 (&acc)[8][4])
{
  __builtin_amdgcn_s_setprio(1);
#pragma unroll
  for (int ks = 0; ks < 2; ++ks)
#pragma unroll
    for (int f = 0; f < 4; ++f)
#pragma unroll
      for (int g = 0; g < 2; ++g)
        acc[MH * 4 + f][NH * 2 + g] = __builtin_amdgcn_mfma_f32_16x16x32_bf16(
            a[f][ks], b[g][ks], acc[MH * 4 + f][NH * 2 + g], 0, 0, 0);
  __builtin_amdgcn_s_setprio(0);
}

__global__ __launch_bounds__(512, 2) void gemm_qkv8(
    const ushort* __restrict__ hb, const ushort* __restrict__ lb,
    const ushort* __restrict__ wkv, const ushort* __restrict__ wq,
    ushort* __restrict__ Kbf, ushort* __restrict__ Vtb, ushort* __restrict__ Qb)
{
  // [buf(2)][mat A/B][half(2)][8192 ushorts] = 128 KiB
  __shared__ __align__(16) ushort smem[65536];
#define LDSA(P, H) (smem + (P) * 32768 + (H) * 8192)
#define LDSB(P, H) (smem + (P) * 32768 + 16384 + (H) * 8192)

  const int tid  = threadIdx.x;
  const int wave = tid >> 6;
  const int lane = tid & 63;
  const int quad = lane >> 4;
  const int l16  = lane & 15;
  const int wm   = wave >> 2;        // 0..1
  const int wn   = wave & 3;         // 0..3
  const int r4   = lane >> 2;
  const int c8   = (lane & 3) * 8;

  // bijective XCD swizzle: 384 blocks, 48 per XCD chunk -> each XCD owns one
  // M-panel (2 MB, L2-resident); B streams via L3.
  const int bid = blockIdx.x;
  const int swz = (bid & 7) * 48 + (bid >> 3);
  const int xt  = swz % 48;
  const int m0  = (swz / 48) * 256;

  const ushort* Ag; const ushort* Bg; int n0;
  if (xt < 32) { Ag = hb; Bg = wkv; n0 = xt * 256; }
  else         { Ag = lb; Bg = wq;  n0 = (xt - 32) * 256; }

  f32x4 acc[8][4];
#pragma unroll
  for (int i = 0; i < 8; ++i)
#pragma unroll
    for (int j = 0; j < 4; ++j) acc[i][j] = {0.f, 0.f, 0.f, 0.f};

  bf16x8 a[4][2], b0[2][2], b1[2][2];

  // ---- prologue: tile 0 (4 halves) + tile 1 (3 halves) -------------------
  stage_half8(Ag, m0,       0,  LDSA(0, 0), wave, r4, c8);   // A h0 t0
  stage_half8(Bg, n0,       0,  LDSB(0, 0), wave, r4, c8);   // B h0 t0
  stage_half8(Bg, n0 + 128, 0,  LDSB(0, 1), wave, r4, c8);   // B h1 t0
  stage_half8(Ag, m0 + 128, 0,  LDSA(0, 1), wave, r4, c8);   // A h1 t0
  stage_half8(Ag, m0,       64, LDSA(1, 0), wave, r4, c8);   // A h0 t1
  stage_half8(Bg, n0,       64, LDSB(1, 0), wave, r4, c8);   // B h0 t1
  stage_half8(Bg, n0 + 128, 64, LDSB(1, 1), wave, r4, c8);   // B h1 t1
  VM6();                 // oldest 8 loads (= tile 0) landed; 3 halves in flight
  BARw();

  // ---- main loop: 2 K-tiles (8 phases) per iteration ---------------------
#pragma unroll 1
  for (int t = 0; t < 64; t += 2) {
    // ======== tile t (buf 0) ========
    // ph1: quadrant (0,0); stage A-h1(t+1)
    read_a8(LDSA(0, 0), wm, l16, quad, a);
    read_b8(LDSB(0, 0), wn, l16, quad, b0);
    stage_half8(Ag, m0 + 128, (t + 1) * 64, LDSA(1, 1), wave, r4, c8);
    BARw(); LGKMW();
    mfma_quad<0, 0>(a, b0, acc);
    BARw();
    // ph2: quadrant (0,1); stage A-h0(t+2)
    read_b8(LDSB(0, 1), wn, l16, quad, b1);
    if (t < 62) stage_half8(Ag, m0, (t + 2) * 64, LDSA(0, 0), wave, r4, c8);
    BARw(); LGKMW();
    mfma_quad<0, 1>(a, b1, acc);
    BARw();
    // ph3: quadrant (1,0); stage B-h0(t+2)
    read_a8(LDSA(0, 1), wm, l16, quad, a);
    if (t < 62) stage_half8(Bg, n0, (t + 2) * 64, LDSB(0, 0), wave, r4, c8);
    BARw(); LGKMW();
    mfma_quad<1, 0>(a, b0, acc);
    BARw();
    // ph4: quadrant (1,1); stage B-h1(t+2); tile boundary wait
    if (t < 62) stage_half8(Bg, n0 + 128, (t + 2) * 64, LDSB(0, 1), wave, r4, c8);
    BARw(); LGKMW();
    mfma_quad<1, 1>(a, b1, acc);
    if (t < 62) VM6(); else VM0();
    BARw();

    // ======== tile t+1 (buf 1) ========
    // ph5: quadrant (0,0); stage A-h1(t+2)
    read_a8(LDSA(1, 0), wm, l16, quad, a);
    read_b8(LDSB(1, 0), wn, l16, quad, b0);
    if (t < 62) stage_half8(Ag, m0 + 128, (t + 2) * 64, LDSA(0, 1), wave, r4, c8);
    BARw(); LGKMW();
    mfma_quad<0, 0>(a, b0, acc);
    BARw();
    // ph6: quadrant (0,1); stage A-h0(t+3)
    read_b8(LDSB(1, 1), wn, l16, quad, b1);
    if (t < 61) stage_half8(Ag, m0, (t + 3) * 64, LDSA(1, 0), wave, r4, c8);
    BARw(); LGKMW();
    mfma_quad<0, 1>(a, b1, acc);
    BARw();
    // ph7: quadrant (1,0); stage B-h0(t+3)
    read_a8(LDSA(1, 1), wm, l16, quad, a);
    if (t < 61) stage_half8(Bg, n0, (t + 3) * 64, LDSB(1, 0), wave, r4, c8);
    BARw(); LGKMW();
    mfma_quad<1, 0>(a, b0, acc);
    BARw();
    // ph8: quadrant (1,1); stage B-h1(t+3); tile boundary wait
    if (t < 61) stage_half8(Bg, n0 + 128, (t + 3) * 64, LDSB(1, 1), wave, r4, c8);
    BARw(); LGKMW();
    mfma_quad<1, 1>(a, b1, acc);
    if (t < 60) { VM6(); } else if (t < 62) { VM0(); }
    BARw();
  }

  // ---- epilogue: route K / V^T / Q ---------------------------------------
  const int route = (xt >= 32) ? 2 : (n0 >= 4096 ? 1 : 0);
#pragma unroll
  for (int fm = 0; fm < 8; ++fm) {
    const int rowb = m0 + (fm >> 2) * 128 + wm * 64 + (fm & 3) * 16 + quad * 4;
#pragma unroll
    for (int fn = 0; fn < 4; ++fn) {
      const int col = n0 + (fn >> 1) * 128 + wn * 32 + (fn & 1) * 16 + l16;
#pragma unroll
      for (int r = 0; r < 4; ++r) {
        const ushort val = f2bf(acc[fm][fn][r]);
        const int row = rowb + r;
        if (route == 0)      Kbf[(size_t)row * 4096 + col] = val;
        else if (route == 1) Vtb[(size_t)(col - 4096) * 2048 + row] = val;
        else                 Qb[(size_t)row * 4096 + col] = val;
      }
    }
  }
#undef LDSA
#undef LDSB
}

// ---------------------------------------------------------------------------
// Split-K GEMM for out = AO * Wo^T : blockIdx.z selects K-half; fp32 partials.
// ---------------------------------------------------------------------------
__global__ __launch_bounds__(256) void gemm_splitk(
    const ushort* __restrict__ A, const ushort* __restrict__ B,
    float* __restrict__ P)  // P[z][2048][4096]
{
  __shared__ __align__(16) ushort As[128 * 32];
  __shared__ __align__(16) ushort Bs[128 * 32];

  const int tid  = threadIdx.x;
  const int wave = tid >> 6;
  const int lane = tid & 63;
  const int quad = lane >> 4;
  const int l16  = lane & 15;
  const int m0 = blockIdx.y * 128;
  const int n0 = blockIdx.x * 128;
  const int K  = 4096;
  const int kb = blockIdx.z * 2048;

  const int wm = (wave & 1) * 64;
  const int wn = (wave >> 1) * 64;
  const int srow = lane >> 2;
  const int scol = (lane & 3) * 8;
  const ushort* ga0 = A + (size_t)(m0 + 32 * wave + srow) * K + scol + kb;
  const ushort* ga1 = ga0 + (size_t)16 * K;
  const ushort* gb0 = B + (size_t)(n0 + 32 * wave + srow) * K + scol + kb;
  const ushort* gb1 = gb0 + (size_t)16 * K;
  ushort* la0 = As + (2 * wave) * 512;
  ushort* la1 = As + (2 * wave + 1) * 512;
  ushort* lb0 = Bs + (2 * wave) * 512;
  ushort* lb1 = Bs + (2 * wave + 1) * 512;

  f32x4 acc[4][4];
#pragma unroll
  for (int i = 0; i < 4; i++)
#pragma unroll
    for (int j = 0; j < 4; j++) acc[i][j] = {0.f, 0.f, 0.f, 0.f};

  for (int k0 = 0; k0 < 2048; k0 += 32) {
    __syncthreads();
    gld16(ga0 + k0, la0);
    gld16(ga1 + k0, la1);
    gld16(gb0 + k0, lb0);
    gld16(gb1 + k0, lb1);
    __syncthreads();

    bf16x8 af[4], bfr[4];
#pragma unroll
    for (int i = 0; i < 4; i++) {
      af[i]  = *(const bf16x8*)(As + (wm + i * 16 + l16) * 32 + quad * 8);
      bfr[i] = *(const bf16x8*)(Bs + (wn + i * 16 + l16) * 32 + quad * 8);
    }
#pragma unroll
    for (int im = 0; im < 4; im++)
#pragma unroll
      for (int in = 0; in < 4; in++)
        acc[im][in] = __builtin_amdgcn_mfma_f32_16x16x32_bf16(
            af[im], bfr[in], acc[im][in], 0, 0, 0);
  }

  float* myP = P + (size_t)blockIdx.z * 2048 * 4096;
#pragma unroll
  for (int im = 0; im < 4; im++)
#pragma unroll
    for (int in = 0; in < 4; in++)
#pragma unroll
      for (int r = 0; r < 4; r++) {
        int row = m0 + wm + im * 16 + quad * 4 + r;
        int col = n0 + wn + in * 16 + l16;
        myP[(size_t)row * 4096 + col] = acc[im][in][r];
      }
}

__global__ __launch_bounds__(256) void reduce2(
    const float* __restrict__ P, float* __restrict__ out, int n4)
{
  int i = blockIdx.x * 256 + threadIdx.x;
  if (i >= n4) return;
  const float4* p0 = (const float4*)P;
  const float4* p1 = (const float4*)(P + (size_t)2048 * 4096);
  float4 a = p0[i], b = p1[i];
  float4 r; r.x = a.x + b.x; r.y = a.y + b.y; r.z = a.z + b.z; r.w = a.w + b.w;
  ((float4*)out)[i] = r;
}

// ---------------------------------------------------------------------------
// FALLBACK GEMM (mixed fp32/bf16 inputs, VGPR staging)
// ---------------------------------------------------------------------------
template <bool TRANSC, typename TA, typename TB, typename TC>
__global__ __launch_bounds__(256) void gemm_bt(
    const TA* __restrict__ A, const TB* __restrict__ B,
    TC* __restrict__ C, int M, int N, int K, int ldc)
{
  __shared__ __align__(16) ushort As[128 * 32];
  __shared__ __align__(16) ushort Bs[128 * 32];

  const int tid  = threadIdx.x;
  const int wave = tid >> 6;
  const int lane = tid & 63;
  const int quad = lane >> 4;
  const int l16  = lane & 15;
  const int m0 = blockIdx.y * 128;
  const int n0 = blockIdx.x * 128;
  const int wm = (wave & 1) * 64;
  const int wn = (wave >> 1) * 64;
  const int r0 = tid >> 2;
  const int c0 = (tid & 3) * 8;

  f32x4 acc[4][4];
#pragma unroll
  for (int i = 0; i < 4; i++)
#pragma unroll
    for (int j = 0; j < 4; j++) acc[i][j] = {0.f, 0.f, 0.f, 0.f};

  const TA* aptr = A + (size_t)(m0 + r0) * K + c0;
  const TB* bptr = B + (size_t)(n0 + r0) * K + c0;

  for (int k0 = 0; k0 < K; k0 += 32) {
    uint4 av0 = ld8(aptr + k0);
    uint4 av1 = ld8(aptr + (size_t)64 * K + k0);
    uint4 bv0 = ld8(bptr + k0);
    uint4 bv1 = ld8(bptr + (size_t)64 * K + k0);
    __syncthreads();
    *(uint4*)(As + r0 * 32 + c0)        = av0;
    *(uint4*)(As + (r0 + 64) * 32 + c0) = av1;
    *(uint4*)(Bs + r0 * 32 + c0)        = bv0;
    *(uint4*)(Bs + (r0 + 64) * 32 + c0) = bv1;
    __syncthreads();

    bf16x8 af[4], bfr[4];
#pragma unroll
    for (int i = 0; i < 4; i++) {
      af[i]  = *(const bf16x8*)(As + (wm + i * 16 + l16) * 32 + quad * 8);
      bfr[i] = *(const bf16x8*)(Bs + (wn + i * 16 + l16) * 32 + quad * 8);
    }
#pragma unroll
    for (int im = 0; im < 4; im++)
#pragma unroll
      for (int in = 0; in < 4; in++)
        acc[im][in] = __builtin_amdgcn_mfma_f32_16x16x32_bf16(
            af[im], bfr[in], acc[im][in], 0, 0, 0);
  }

#pragma unroll
  for (int im = 0; im < 4; im++)
#pragma unroll
    for (int in = 0; in < 4; in++)
#pragma unroll
      for (int r = 0; r < 4; r++) {
        int row = m0 + wm + im * 16 + quad * 4 + r;
        int col = n0 + wn + in * 16 + l16;
        float fv = acc[im][in][r];
        TC val;
        if constexpr (std::is_same<TC, ushort>::value) val = f2bf(fv);
        else                                           val = fv;
        if (TRANSC) C[(size_t)col * ldc + row] = val;
        else        C[(size_t)row * ldc + col] = val;
      }
}

// ---------------------------------------------------------------------------
// RoPE on K (bf16) in place
// ---------------------------------------------------------------------------
__global__ __launch_bounds__(256) void rope_kernel(ushort* __restrict__ Kb)
{
  int idx = blockIdx.x * 256 + threadIdx.x;
  int j  = idx & 63;
  int hs = idx >> 6;
  int s  = hs >> 5;
  float freq = expf(-0.14391156f * (float)j);
  float ang  = (float)s * freq;
  float sn, c;
  sincosf(ang, &sn, &c);
  size_t base = (size_t)hs * 128 + j;
  float k1 = bf2f(Kb[base]);
  float k2 = bf2f(Kb[base + 64]);
  Kb[base]      = f2bf(k1 * c - k2 * sn);
  Kb[base + 64] = f2bf(k2 * c + k1 * sn);
}

// ---------------------------------------------------------------------------
// Flash attention (round-2 proven version): block = 1 head x 64 q rows,
// 128-key tiles, 80KB LDS, grid 32x32 = 1024 blocks.
// ---------------------------------------------------------------------------
__global__ __launch_bounds__(256) void flash_attn(
    const ushort* __restrict__ Q, const ushort* __restrict__ Kb,
    const ushort* __restrict__ Vt, ushort* __restrict__ AO)
{
  __shared__ __align__(16) ushort Kt[128 * 128];
  __shared__ __align__(16) ushort Vs[128 * 128];
  __shared__ __align__(16) ushort Ps[4][16 * 128];

  const int tid  = threadIdx.x;
  const int wave = tid >> 6;
  const int lane = tid & 63;
  const int quad = lane >> 4;
  const int l16  = lane & 15;
  const int h  = blockIdx.y;
  const int q0 = blockIdx.x * 64 + wave * 16;
  const float scale = 0.08838834764831845f;

  bf16x8 aq[4];
#pragma unroll
  for (int kt = 0; kt < 4; kt++)
    aq[kt] = *(const bf16x8*)(Q + (size_t)(q0 + l16) * 4096 + h * 128 + kt * 32 + quad * 8);

  f32x4 Oacc[8];
#pragma unroll
  for (int dt = 0; dt < 8; dt++) Oacc[dt] = {0.f, 0.f, 0.f, 0.f};
  float m_i[4], l_i[4];
#pragma unroll
  for (int r = 0; r < 4; r++) { m_i[r] = -1e30f; l_i[r] = 0.f; }

  ushort* myP = &Ps[wave][0];

  for (int kv = 0; kv < 2048; kv += 128) {
    __syncthreads();
#pragma unroll
    for (int it = 0; it < 8; it++) {
      int i   = tid + it * 256;
      int row = i >> 4;
      int g   = i & 15;
      int sw  = (g ^ (row & 15)) * 8;
      *(uint4*)(Kt + row * 128 + sw) =
          *(const uint4*)(Kb + (size_t)(kv + row) * 4096 + h * 128 + g * 8);
      *(uint4*)(Vs + row * 128 + sw) =
          *(const uint4*)(Vt + (size_t)(h * 128 + row) * 2048 + kv + g * 8);
    }
    __syncthreads();

    f32x4 sA[8];
#pragma unroll
    for (int nt = 0; nt < 8; nt++) sA[nt] = {0.f, 0.f, 0.f, 0.f};
#pragma unroll
    for (int nt = 0; nt < 8; nt++) {
      int row = nt * 16 + l16;
#pragma unroll
      for (int kt = 0; kt < 4; kt++) {
        int g = kt * 4 + quad;
        bf16x8 bk = *(const bf16x8*)(Kt + row * 128 + ((g ^ (row & 15)) * 8));
        sA[nt] = __builtin_amdgcn_mfma_f32_16x16x32_bf16(aq[kt], bk, sA[nt], 0, 0, 0);
      }
    }

    float tmax[4];
#pragma unroll
    for (int r = 0; r < 4; r++) {
      float m = sA[0][r];
#pragma unroll
      for (int nt = 1; nt < 8; nt++) m = fmaxf(m, sA[nt][r]);
      tmax[r] = m;
    }
#pragma unroll
    for (int msk = 1; msk < 16; msk <<= 1)
#pragma unroll
      for (int r = 0; r < 4; r++)
        tmax[r] = fmaxf(tmax[r], __shfl_xor(tmax[r], msk));

    float alpha[4];
#pragma unroll
    for (int r = 0; r < 4; r++) {
      float mn = fmaxf(m_i[r], tmax[r] * scale);
      alpha[r] = __expf(m_i[r] - mn);
      m_i[r] = mn;
    }
    float rsum[4] = {0.f, 0.f, 0.f, 0.f};
#pragma unroll
    for (int nt = 0; nt < 8; nt++)
#pragma unroll
      for (int r = 0; r < 4; r++) {
        float p = __expf(sA[nt][r] * scale - m_i[r]);
        sA[nt][r] = p;
        rsum[r] += p;
      }
#pragma unroll
    for (int msk = 1; msk < 16; msk <<= 1)
#pragma unroll
      for (int r = 0; r < 4; r++) rsum[r] += __shfl_xor(rsum[r], msk);
#pragma unroll
    for (int r = 0; r < 4; r++) l_i[r] = l_i[r] * alpha[r] + rsum[r];

#pragma unroll
    for (int nt = 0; nt < 8; nt++)
#pragma unroll
      for (int r = 0; r < 4; r++) {
        int row = quad * 4 + r;
        int col = nt * 16 + l16;
        myP[row * 128 + (((col >> 3) ^ row) * 8) + (col & 7)] = f2bf(sA[nt][r]);
      }

#pragma unroll
    for (int dt = 0; dt < 8; dt++)
#pragma unroll
      for (int r = 0; r < 4; r++) Oacc[dt][r] *= alpha[r];

#pragma unroll
    for (int kt = 0; kt < 4; kt++) {
      int g = kt * 4 + quad;
      bf16x8 ap = *(const bf16x8*)(myP + l16 * 128 + ((g ^ l16) * 8));
#pragma unroll
      for (int dt = 0; dt < 8; dt++) {
        int vrow = dt * 16 + l16;
        bf16x8 bv = *(const bf16x8*)(Vs + vrow * 128 + ((g ^ (vrow & 15)) * 8));
        Oacc[dt] = __builtin_amdgcn_mfma_f32_16x16x32_bf16(ap, bv, Oacc[dt], 0, 0, 0);
      }
    }
  }

#pragma unroll
  for (int dt = 0; dt < 8; dt++)
#pragma unroll
    for (int r = 0; r < 4; r++) {
      int row = q0 + quad * 4 + r;
      int col = h * 128 + dt * 16 + l16;
      AO[(size_t)row * 4096 + col] = f2bf(Oacc[dt][r] / l_i[r]);
    }
}

// ---------------------------------------------------------------------------
extern "C" void kernel_launch(void* const* d_in, const int* in_sizes, int n_in,
                              void* d_out, int out_size, void* d_ws, size_t ws_size,
                              hipStream_t stream)
{
  const float* hidden  = (const float*)d_in[0];
  const float* Wq      = (const float*)d_in[2];
  const float* Wk      = (const float*)d_in[3];
  const float* Wv      = (const float*)d_in[4];
  const float* Wo      = (const float*)d_in[5];
  const float* latents = (const float*)d_in[6];
  float* out = (float*)d_out;

  const size_t SB = (size_t)2048 * 4096 * 2;  // 16 MiB
  char* w = (char*)d_ws;
  const int n8_act = 2048 * 4096 / 8;
  const int n8_wt  = 4096 * 4096 / 8;

  if (ws_size >= 13 * SB) {
    ushort* hb  = (ushort*)(w);
    ushort* lb  = (ushort*)(w + 1 * SB);
    ushort* wqb = (ushort*)(w + 2 * SB);   // 2 SB
    ushort* wkv = (ushort*)(w + 4 * SB);   // 4 SB: [Wk;Wv] stacked [8192,4096]
    ushort* wob = (ushort*)(w + 8 * SB);   // 2 SB
    ushort* Qb  = (ushort*)(w + 10 * SB);
    ushort* Kbf = (ushort*)(w + 11 * SB);
    ushort* Vtb = (ushort*)(w + 12 * SB);
    ushort* AOb = wqb;                      // reuse after QKV GEMM
    float*  Pp  = (float*)(w + 4 * SB);     // 64MB partials, reuse wkv region

    cvt_bf16<<<n8_act / 256, 256, 0, stream>>>(hidden,  hb,  n8_act);
    cvt_bf16<<<n8_act / 256, 256, 0, stream>>>(latents, lb,  n8_act);
    cvt_bf16<<<n8_wt / 256, 256, 0, stream>>>(Wq, wqb, n8_wt);
    cvt_bf16<<<n8_wt / 256, 256, 0, stream>>>(Wk, wkv, n8_wt);
    cvt_bf16<<<n8_wt / 256, 256, 0, stream>>>(Wv, wkv + (size_t)4096 * 4096, n8_wt);
    cvt_bf16<<<n8_wt / 256, 256, 0, stream>>>(Wo, wob, n8_wt);

    gemm_qkv8<<<dim3(384), 512, 0, stream>>>(hb, lb, wkv, wqb, Kbf, Vtb, Qb);
    rope_kernel<<<(2048 * 32 * 64) / 256, 256, 0, stream>>>(Kbf);
    flash_attn<<<dim3(32, 32), 256, 0, stream>>>(Qb, Kbf, Vtb, AOb);
    gemm_splitk<<<dim3(32, 16, 2), 256, 0, stream>>>(AOb, wob, Pp);
    reduce2<<<(2048 * 4096 / 4 + 255) / 256, 256, 0, stream>>>(Pp, out, 2048 * 4096 / 4);
  } else {
    ushort* Qb  = (ushort*)(w);
    ushort* Kbf = (ushort*)(w + 1 * SB);
    ushort* Vtb = (ushort*)(w + 2 * SB);
    ushort* AOb = (ushort*)(w + 3 * SB);

    gemm_bt<false><<<dim3(32, 16), 256, 0, stream>>>(latents, Wq, Qb, 2048, 4096, 4096, 4096);
    gemm_bt<false><<<dim3(32, 16), 256, 0, stream>>>(hidden, Wk, Kbf, 2048, 4096, 4096, 4096);
    gemm_bt<true><<<dim3(32, 16), 256, 0, stream>>>(hidden, Wv, Vtb, 2048, 4096, 4096, 2048);
    rope_kernel<<<(2048 * 32 * 64) / 256, 256, 0, stream>>>(Kbf);
    flash_attn<<<dim3(32, 32), 256, 0, stream>>>(Qb, Kbf, Vtb, AOb);
    gemm_bt<false><<<dim3(32, 16), 256, 0, stream>>>(AOb, Wo, out, 2048, 4096, 4096, 4096);
  }
}

// Round 2
// 840.958 us; speedup vs baseline: 1.2304x; 1.1296x over previous
//
#include <hip/hip_runtime.h>
#include <cstdint>
#include <type_traits>

typedef short bf16x8 __attribute__((ext_vector_type(8)));
typedef float f32x4 __attribute__((ext_vector_type(4)));

__device__ __forceinline__ ushort f2bf(float f) {
  union { float f; uint32_t u; } v; v.f = f;
  return (ushort)((v.u + 0x7fffu + ((v.u >> 16) & 1u)) >> 16);
}
__device__ __forceinline__ float bf2f(ushort u) {
  union { uint32_t u; float f; } v; v.u = ((uint32_t)u) << 16;
  return v.f;
}
__device__ __forceinline__ uint32_t pkbf(float x, float y) {
  uint32_t ux = (__float_as_uint(x) + 0x8000u) >> 16;
  uint32_t uy = (__float_as_uint(y) + 0x8000u) & 0xffff0000u;
  return ux | uy;
}

// async global->LDS, 16B per lane; LDS base must be wave-uniform,
// HW writes lane l at base + l*16.
__device__ __forceinline__ void gld16(const void* g, void* l) {
  __builtin_amdgcn_global_load_lds(
      (__attribute__((address_space(1))) void*)(g),
      (__attribute__((address_space(3))) void*)(l), 16, 0, 0);
}

__device__ __forceinline__ uint4 ld8(const ushort* p) { return *(const uint4*)p; }
__device__ __forceinline__ uint4 ld8(const float* p) {
  float4 a = *(const float4*)p;
  float4 b = *(const float4*)(p + 4);
  uint4 r;
  r.x = pkbf(a.x, a.y); r.y = pkbf(a.z, a.w);
  r.z = pkbf(b.x, b.y); r.w = pkbf(b.z, b.w);
  return r;
}

// ---------------------------------------------------------------------------
// fp32 -> bf16 bulk convert: 8 elements/thread
// ---------------------------------------------------------------------------
__global__ __launch_bounds__(256) void cvt_bf16(
    const float* __restrict__ src, ushort* __restrict__ dst, int n8)
{
  int i = blockIdx.x * 256 + threadIdx.x;
  if (i >= n8) return;
  const float4* s = (const float4*)src;
  float4 a = s[2 * i], b = s[2 * i + 1];
  uint4 r;
  r.x = pkbf(a.x, a.y); r.y = pkbf(a.z, a.w);
  r.z = pkbf(b.x, b.y); r.w = pkbf(b.z, b.w);
  ((uint4*)dst)[i] = r;
}

// ===========================================================================
// 256x256 8-phase GEMM template (m201-style), 512 threads = 8 waves (2Mx4N),
// BK=64, 128 KiB LDS, counted vmcnt(6), setprio, subtiled conflict-free LDS.
// MODE 0: QKV fused (A in {hb,lb}, B in {wkv,wq}; route K / V^T / Q, bf16 out)
// MODE 1: split-K out-GEMM (A=AO, B=Wo; kz selects K-half; fp32 partials)
// NT = number of BK=64 K-tiles.
// ===========================================================================

#define BARw() __builtin_amdgcn_s_barrier()
#define LGKMW() do { asm volatile("s_waitcnt lgkmcnt(0)" ::: "memory"); \
                     __builtin_amdgcn_sched_barrier(0); } while (0)
#define VM6() asm volatile("s_waitcnt vmcnt(6)" ::: "memory")
#define VM0() asm volatile("s_waitcnt vmcnt(0)" ::: "memory")

// Stage one 128x64 half-tile (16 KiB) into LDS (subtile layout).
__device__ __forceinline__ void stage_half8(
    const ushort* __restrict__ G, int row0, int col0,
    ushort* lds, int wave, int r4, int c8)
{
#pragma unroll
  for (int q = 0; q < 2; ++q) {
    const int si = q * 8 + wave;
    const ushort* g = G + (size_t)(row0 + (si >> 1) * 16 + r4) * 4096
                        + (col0 + (si & 1) * 32 + c8);
    gld16(g, lds + si * 512);
  }
}

// A-fragment reads: 4 m-frags x 2 k-steps from one half (8 x ds_read_b128).
__device__ __forceinline__ void read_a8(const ushort* base, int wm, int l16,
                                        int quad, bf16x8 (&a)[4][2])
{
#pragma unroll
  for (int f = 0; f < 4; ++f)
#pragma unroll
    for (int ks = 0; ks < 2; ++ks)
      a[f][ks] = *(const bf16x8*)(base + ((wm * 4 + f) * 2 + ks) * 512
                                       + l16 * 32 + quad * 8);
}

// B-fragment reads: 2 n-frags x 2 k-steps from one half (4 x ds_read_b128).
__device__ __forceinline__ void read_b8(const ushort* base, int wn, int l16,
                                        int quad, bf16x8 (&b)[2][2])
{
#pragma unroll
  for (int f = 0; f < 2; ++f)
#pragma unroll
    for (int ks = 0; ks < 2; ++ks)
      b[f][ks] = *(const bf16x8*)(base + ((wn * 2 + f) * 2 + ks) * 512
                                       + l16 * 32 + quad * 8);
}

template <int MH, int NH>
__device__ __forceinline__ void mfma_quad(const bf16x8 (&a)[4][2],
                                          const bf16x8 (&b)[2][2],
                                          f32x4 (&acc)[8][4])
{
  __builtin_amdgcn_s_setprio(1);
#pragma unroll
  for (int ks = 0; ks < 2; ++ks)
#pragma unroll
    for (int f = 0; f < 4; ++f)
#pragma unroll
      for (int g = 0; g < 2; ++g)
        acc[MH * 4 + f][NH * 2 + g] = __builtin_amdgcn_mfma_f32_16x16x32_bf16(
            a[f][ks], b[g][ks], acc[MH * 4 + f][NH * 2 + g], 0, 0, 0);
  __builtin_amdgcn_s_setprio(0);
}

template <int NT, int MODE>
__global__ __launch_bounds__(512, 2) void gemm8(
    const ushort* __restrict__ A0, const ushort* __restrict__ A1,
    const ushort* __restrict__ B0, const ushort* __restrict__ B1,
    ushort* __restrict__ O0, ushort* __restrict__ O1, ushort* __restrict__ O2,
    float* __restrict__ PF)
{
  // [buf(2)][mat A/B][half(2)][8192 ushorts] = 128 KiB
  __shared__ __align__(16) ushort smem[65536];
#define LDSA(P, H) (smem + (P) * 32768 + (H) * 8192)
#define LDSB(P, H) (smem + (P) * 32768 + 16384 + (H) * 8192)

  const int tid  = threadIdx.x;
  const int wave = tid >> 6;
  const int lane = tid & 63;
  const int quad = lane >> 4;
  const int l16  = lane & 15;
  const int wm   = wave >> 2;        // 0..1
  const int wn   = wave & 3;         // 0..3
  const int r4   = lane >> 2;
  const int c8   = (lane & 3) * 8;

  const int bid = blockIdx.x;
  const ushort* Ag; const ushort* Bg;
  int m0, n0, kbase = 0, route = 0, kz = 0;
  if constexpr (MODE == 0) {
    // 384 blocks, bijective XCD swizzle (48 per XCD chunk)
    const int swz = (bid & 7) * 48 + (bid >> 3);
    const int xt  = swz % 48;
    m0 = (swz / 48) * 256;
    if (xt < 32) { Ag = A0; Bg = B0; n0 = xt * 256; }
    else         { Ag = A1; Bg = B1; n0 = (xt - 32) * 256; }
    route = (xt >= 32) ? 2 : (n0 >= 4096 ? 1 : 0);
  } else {
    // 256 blocks, bijective XCD swizzle (32 per XCD chunk)
    const int swz = (bid & 7) * 32 + (bid >> 3);
    kz = swz >> 7;
    const int r = swz & 127;
    m0 = (r >> 4) * 256;
    n0 = (r & 15) * 256;
    kbase = kz * 2048;
    Ag = A0; Bg = B0;
  }

  f32x4 acc[8][4];
#pragma unroll
  for (int i = 0; i < 8; ++i)
#pragma unroll
    for (int j = 0; j < 4; ++j) acc[i][j] = {0.f, 0.f, 0.f, 0.f};

  bf16x8 a[4][2], b0[2][2], b1[2][2];

  // ---- prologue: tile 0 (4 halves) + tile 1 (3 halves) -------------------
  stage_half8(Ag, m0,       kbase,      LDSA(0, 0), wave, r4, c8);
  stage_half8(Bg, n0,       kbase,      LDSB(0, 0), wave, r4, c8);
  stage_half8(Bg, n0 + 128, kbase,      LDSB(0, 1), wave, r4, c8);
  stage_half8(Ag, m0 + 128, kbase,      LDSA(0, 1), wave, r4, c8);
  stage_half8(Ag, m0,       kbase + 64, LDSA(1, 0), wave, r4, c8);
  stage_half8(Bg, n0,       kbase + 64, LDSB(1, 0), wave, r4, c8);
  stage_half8(Bg, n0 + 128, kbase + 64, LDSB(1, 1), wave, r4, c8);
  VM6();                 // oldest 8 loads (= tile 0) landed; 3 halves in flight
  BARw();

  // ---- main loop: 2 K-tiles (8 phases) per iteration ---------------------
#pragma unroll 1
  for (int t = 0; t < NT; t += 2) {
    // ======== tile t (buf 0) ========
    read_a8(LDSA(0, 0), wm, l16, quad, a);
    read_b8(LDSB(0, 0), wn, l16, quad, b0);
    stage_half8(Ag, m0 + 128, kbase + (t + 1) * 64, LDSA(1, 1), wave, r4, c8);
    BARw(); LGKMW();
    mfma_quad<0, 0>(a, b0, acc);
    BARw();

    read_b8(LDSB(0, 1), wn, l16, quad, b1);
    if (t < NT - 2) stage_half8(Ag, m0, kbase + (t + 2) * 64, LDSA(0, 0), wave, r4, c8);
    BARw(); LGKMW();
    mfma_quad<0, 1>(a, b1, acc);
    BARw();

    read_a8(LDSA(0, 1), wm, l16, quad, a);
    if (t < NT - 2) stage_half8(Bg, n0, kbase + (t + 2) * 64, LDSB(0, 0), wave, r4, c8);
    BARw(); LGKMW();
    mfma_quad<1, 0>(a, b0, acc);
    BARw();

    if (t < NT - 2) stage_half8(Bg, n0 + 128, kbase + (t + 2) * 64, LDSB(0, 1), wave, r4, c8);
    BARw(); LGKMW();
    mfma_quad<1, 1>(a, b1, acc);
    if (t < NT - 2) VM6(); else VM0();
    BARw();

    // ======== tile t+1 (buf 1) ========
    read_a8(LDSA(1, 0), wm, l16, quad, a);
    read_b8(LDSB(1, 0), wn, l16, quad, b0);
    if (t < NT - 2) stage_half8(Ag, m0 + 128, kbase + (t + 2) * 64, LDSA(0, 1), wave, r4, c8);
    BARw(); LGKMW();
    mfma_quad<0, 0>(a, b0, acc);
    BARw();

    read_b8(LDSB(1, 1), wn, l16, quad, b1);
    if (t < NT - 3) stage_half8(Ag, m0, kbase + (t + 3) * 64, LDSA(1, 0), wave, r4, c8);
    BARw(); LGKMW();
    mfma_quad<0, 1>(a, b1, acc);
    BARw();

    read_a8(LDSA(1, 1), wm, l16, quad, a);
    if (t < NT - 3) stage_half8(Bg, n0, kbase + (t + 3) * 64, LDSB(1, 0), wave, r4, c8);
    BARw(); LGKMW();
    mfma_quad<1, 0>(a, b0, acc);
    BARw();

    if (t < NT - 3) stage_half8(Bg, n0 + 128, kbase + (t + 3) * 64, LDSB(1, 1), wave, r4, c8);
    BARw(); LGKMW();
    mfma_quad<1, 1>(a, b1, acc);
    if (t < NT - 4) { VM6(); } else if (t < NT - 2) { VM0(); }
    BARw();
  }

  // ---- epilogue ----------------------------------------------------------
  if constexpr (MODE == 0) {
#pragma unroll
    for (int fm = 0; fm < 8; ++fm) {
      const int rowb = m0 + (fm >> 2) * 128 + wm * 64 + (fm & 3) * 16 + quad * 4;
#pragma unroll
      for (int fn = 0; fn < 4; ++fn) {
        const int col = n0 + (fn >> 1) * 128 + wn * 32 + (fn & 1) * 16 + l16;
#pragma unroll
        for (int r = 0; r < 4; ++r) {
          const ushort val = f2bf(acc[fm][fn][r]);
          const int row = rowb + r;
          if (route == 0)      O0[(size_t)row * 4096 + col] = val;
          else if (route == 1) O1[(size_t)(col - 4096) * 2048 + row] = val;
          else                 O2[(size_t)row * 4096 + col] = val;
        }
      }
    }
  } else {
    float* myP = PF + (size_t)kz * 2048 * 4096;
#pragma unroll
    for (int fm = 0; fm < 8; ++fm) {
      const int rowb = m0 + (fm >> 2) * 128 + wm * 64 + (fm & 3) * 16 + quad * 4;
#pragma unroll
      for (int fn = 0; fn < 4; ++fn) {
        const int col = n0 + (fn >> 1) * 128 + wn * 32 + (fn & 1) * 16 + l16;
#pragma unroll
        for (int r = 0; r < 4; ++r)
          myP[(size_t)(rowb + r) * 4096 + col] = acc[fm][fn][r];
      }
    }
  }
#undef LDSA
#undef LDSB
}

__global__ __launch_bounds__(256) void reduce2(
    const float* __restrict__ P, float* __restrict__ out, int n4)
{
  int i = blockIdx.x * 256 + threadIdx.x;
  if (i >= n4) return;
  const float4* p0 = (const float4*)P;
  const float4* p1 = (const float4*)(P + (size_t)2048 * 4096);
  float4 a = p0[i], b = p1[i];
  float4 r; r.x = a.x + b.x; r.y = a.y + b.y; r.z = a.z + b.z; r.w = a.w + b.w;
  ((float4*)out)[i] = r;
}

// ---------------------------------------------------------------------------
// FALLBACK GEMM (mixed fp32/bf16 inputs, VGPR staging)
// ---------------------------------------------------------------------------
template <bool TRANSC, typename TA, typename TB, typename TC>
__global__ __launch_bounds__(256) void gemm_bt(
    const TA* __restrict__ A, const TB* __restrict__ B,
    TC* __restrict__ C, int M, int N, int K, int ldc)
{
  __shared__ __align__(16) ushort As[128 * 32];
  __shared__ __align__(16) ushort Bs[128 * 32];

  const int tid  = threadIdx.x;
  const int wave = tid >> 6;
  const int lane = tid & 63;
  const int quad = lane >> 4;
  const int l16  = lane & 15;
  const int m0 = blockIdx.y * 128;
  const int n0 = blockIdx.x * 128;
  const int wm = (wave & 1) * 64;
  const int wn = (wave >> 1) * 64;
  const int r0 = tid >> 2;
  const int c0 = (tid & 3) * 8;

  f32x4 acc[4][4];
#pragma unroll
  for (int i = 0; i < 4; i++)
#pragma unroll
    for (int j = 0; j < 4; j++) acc[i][j] = {0.f, 0.f, 0.f, 0.f};

  const TA* aptr = A + (size_t)(m0 + r0) * K + c0;
  const TB* bptr = B + (size_t)(n0 + r0) * K + c0;

  for (int k0 = 0; k0 < K; k0 += 32) {
    uint4 av0 = ld8(aptr + k0);
    uint4 av1 = ld8(aptr + (size_t)64 * K + k0);
    uint4 bv0 = ld8(bptr + k0);
    uint4 bv1 = ld8(bptr + (size_t)64 * K + k0);
    __syncthreads();
    *(uint4*)(As + r0 * 32 + c0)        = av0;
    *(uint4*)(As + (r0 + 64) * 32 + c0) = av1;
    *(uint4*)(Bs + r0 * 32 + c0)        = bv0;
    *(uint4*)(Bs + (r0 + 64) * 32 + c0) = bv1;
    __syncthreads();

    bf16x8 af[4], bfr[4];
#pragma unroll
    for (int i = 0; i < 4; i++) {
      af[i]  = *(const bf16x8*)(As + (wm + i * 16 + l16) * 32 + quad * 8);
      bfr[i] = *(const bf16x8*)(Bs + (wn + i * 16 + l16) * 32 + quad * 8);
    }
#pragma unroll
    for (int im = 0; im < 4; im++)
#pragma unroll
      for (int in = 0; in < 4; in++)
        acc[im][in] = __builtin_amdgcn_mfma_f32_16x16x32_bf16(
            af[im], bfr[in], acc[im][in], 0, 0, 0);
  }

#pragma unroll
  for (int im = 0; im < 4; im++)
#pragma unroll
    for (int in = 0; in < 4; in++)
#pragma unroll
      for (int r = 0; r < 4; r++) {
        int row = m0 + wm + im * 16 + quad * 4 + r;
        int col = n0 + wn + in * 16 + l16;
        float fv = acc[im][in][r];
        TC val;
        if constexpr (std::is_same<TC, ushort>::value) val = f2bf(fv);
        else                                           val = fv;
        if (TRANSC) C[(size_t)col * ldc + row] = val;
        else        C[(size_t)row * ldc + col] = val;
      }
}

// ---------------------------------------------------------------------------
// RoPE on K (bf16) in place
// ---------------------------------------------------------------------------
__global__ __launch_bounds__(256) void rope_kernel(ushort* __restrict__ Kb)
{
  int idx = blockIdx.x * 256 + threadIdx.x;
  int j  = idx & 63;
  int hs = idx >> 6;
  int s  = hs >> 5;
  float freq = expf(-0.14391156f * (float)j);
  float ang  = (float)s * freq;
  float sn, c;
  sincosf(ang, &sn, &c);
  size_t base = (size_t)hs * 128 + j;
  float k1 = bf2f(Kb[base]);
  float k2 = bf2f(Kb[base + 64]);
  Kb[base]      = f2bf(k1 * c - k2 * sn);
  Kb[base + 64] = f2bf(k2 * c + k1 * sn);
}

// ---------------------------------------------------------------------------
// Flash attention v2: 512 threads = 8 waves, 1 head x 128 q rows per block,
// 128-key tiles, async-STAGE (T14), setprio (T5), defer-max (T13).
// LDS: K 32K + V 32K + P 32K = 96 KiB. Grid (16, 32).
// ---------------------------------------------------------------------------
__global__ __launch_bounds__(512, 2) void flash_attn(
    const ushort* __restrict__ Q, const ushort* __restrict__ Kb,
    const ushort* __restrict__ Vt, ushort* __restrict__ AO)
{
  __shared__ __align__(16) ushort Kt[128 * 128];
  __shared__ __align__(16) ushort Vs[128 * 128];
  __shared__ __align__(16) ushort Ps[8][16 * 128];

  const int tid  = threadIdx.x;
  const int wave = tid >> 6;
  const int lane = tid & 63;
  const int quad = lane >> 4;
  const int l16  = lane & 15;
  const int h  = blockIdx.y;
  const int q0 = blockIdx.x * 128 + wave * 16;
  const float scale = 0.08838834764831845f;

  bf16x8 aq[4];
#pragma unroll
  for (int kt = 0; kt < 4; kt++)
    aq[kt] = *(const bf16x8*)(Q + (size_t)(q0 + l16) * 4096 + h * 128 + kt * 32 + quad * 8);

  f32x4 Oacc[8];
#pragma unroll
  for (int dt = 0; dt < 8; dt++) Oacc[dt] = {0.f, 0.f, 0.f, 0.f};
  float m_i[4], l_i[4];
#pragma unroll
  for (int r = 0; r < 4; r++) { m_i[r] = -1e30f; l_i[r] = 0.f; }

  ushort* myP = &Ps[wave][0];

  // T14: prefetch registers for next K/V tile (4 x 16B each)
  uint4 kr[4], vr[4];
#pragma unroll
  for (int it = 0; it < 4; ++it) {
    int i = tid + it * 512;
    int row = i >> 4, g = i & 15;
    kr[it] = *(const uint4*)(Kb + (size_t)row * 4096 + h * 128 + g * 8);
    vr[it] = *(const uint4*)(Vt + (size_t)(h * 128 + row) * 2048 + g * 8);
  }

  for (int kv = 0; kv < 2048; kv += 128) {
    __syncthreads();   // previous compute done reading LDS
#pragma unroll
    for (int it = 0; it < 4; ++it) {
      int i = tid + it * 512;
      int row = i >> 4, g = i & 15;
      int sw = (g ^ (row & 15)) * 8;
      *(uint4*)(Kt + row * 128 + sw) = kr[it];
      *(uint4*)(Vs + row * 128 + sw) = vr[it];
    }
    __syncthreads();

    // issue next tile's global loads early; they complete during compute
    if (kv + 128 < 2048) {
#pragma unroll
      for (int it = 0; it < 4; ++it) {
        int i = tid + it * 512;
        int row = i >> 4, g = i & 15;
        kr[it] = *(const uint4*)(Kb + (size_t)(kv + 128 + row) * 4096 + h * 128 + g * 8);
        vr[it] = *(const uint4*)(Vt + (size_t)(h * 128 + row) * 2048 + kv + 128 + g * 8);
      }
    }

    // ---- QK^T -----------------------------------------------------------
    f32x4 sA[8];
#pragma unroll
    for (int nt = 0; nt < 8; nt++) sA[nt] = {0.f, 0.f, 0.f, 0.f};
    __builtin_amdgcn_s_setprio(1);
#pragma unroll
    for (int nt = 0; nt < 8; nt++) {
      int row = nt * 16 + l16;
#pragma unroll
      for (int kt = 0; kt < 4; kt++) {
        int g = kt * 4 + quad;
        bf16x8 bk = *(const bf16x8*)(Kt + row * 128 + ((g ^ (row & 15)) * 8));
        sA[nt] = __builtin_amdgcn_mfma_f32_16x16x32_bf16(aq[kt], bk, sA[nt], 0, 0, 0);
      }
    }
    __builtin_amdgcn_s_setprio(0);

    // ---- online softmax with defer-max (T13, THR=8) ---------------------
    float tmax[4];
#pragma unroll
    for (int r = 0; r < 4; r++) {
      float m = sA[0][r];
#pragma unroll
      for (int nt = 1; nt < 8; nt++) m = fmaxf(m, sA[nt][r]);
      tmax[r] = m;
    }
#pragma unroll
    for (int msk = 1; msk < 16; msk <<= 1)
#pragma unroll
      for (int r = 0; r < 4; r++)
        tmax[r] = fmaxf(tmax[r], __shfl_xor(tmax[r], msk));

    float nm[4];
    float growth = -1e30f;
#pragma unroll
    for (int r = 0; r < 4; r++) {
      nm[r] = tmax[r] * scale;
      growth = fmaxf(growth, nm[r] - m_i[r]);
    }
    if (__any(growth > 8.0f)) {
#pragma unroll
      for (int r = 0; r < 4; r++) {
        float mn = fmaxf(m_i[r], nm[r]);
        float al = __expf(m_i[r] - mn);
        m_i[r] = mn;
        l_i[r] *= al;
#pragma unroll
        for (int dt = 0; dt < 8; dt++) Oacc[dt][r] *= al;
      }
    }

    float rsum[4] = {0.f, 0.f, 0.f, 0.f};
#pragma unroll
    for (int nt = 0; nt < 8; nt++)
#pragma unroll
      for (int r = 0; r < 4; r++) {
        float p = __expf(sA[nt][r] * scale - m_i[r]);
        sA[nt][r] = p;
        rsum[r] += p;
      }
#pragma unroll
    for (int msk = 1; msk < 16; msk <<= 1)
#pragma unroll
      for (int r = 0; r < 4; r++) rsum[r] += __shfl_xor(rsum[r], msk);
#pragma unroll
    for (int r = 0; r < 4; r++) l_i[r] += rsum[r];

    // ---- P -> LDS (swizzled) --------------------------------------------
#pragma unroll
    for (int nt = 0; nt < 8; nt++)
#pragma unroll
      for (int r = 0; r < 4; r++) {
        int row = quad * 4 + r;
        int col = nt * 16 + l16;
        myP[row * 128 + (((col >> 3) ^ row) * 8) + (col & 7)] = f2bf(sA[nt][r]);
      }

    // ---- PV ---------------------------------------------------------------
    __builtin_amdgcn_s_setprio(1);
#pragma unroll
    for (int kt = 0; kt < 4; kt++) {
      int g = kt * 4 + quad;
      bf16x8 ap = *(const bf16x8*)(myP + l16 * 128 + ((g ^ l16) * 8));
#pragma unroll
      for (int dt = 0; dt < 8; dt++) {
        int vrow = dt * 16 + l16;
        bf16x8 bv = *(const bf16x8*)(Vs + vrow * 128 + ((g ^ (vrow & 15)) * 8));
        Oacc[dt] = __builtin_amdgcn_mfma_f32_16x16x32_bf16(ap, bv, Oacc[dt], 0, 0, 0);
      }
    }
    __builtin_amdgcn_s_setprio(0);
  }

#pragma unroll
  for (int dt = 0; dt < 8; dt++)
#pragma unroll
    for (int r = 0; r < 4; r++) {
      int row = q0 + quad * 4 + r;
      int col = h * 128 + dt * 16 + l16;
      AO[(size_t)row * 4096 + col] = f2bf(Oacc[dt][r] / l_i[r]);
    }
}

// ---------------------------------------------------------------------------
extern "C" void kernel_launch(void* const* d_in, const int* in_sizes, int n_in,
                              void* d_out, int out_size, void* d_ws, size_t ws_size,
                              hipStream_t stream)
{
  const float* hidden  = (const float*)d_in[0];
  const float* Wq      = (const float*)d_in[2];
  const float* Wk      = (const float*)d_in[3];
  const float* Wv      = (const float*)d_in[4];
  const float* Wo      = (const float*)d_in[5];
  const float* latents = (const float*)d_in[6];
  float* out = (float*)d_out;

  const size_t SB = (size_t)2048 * 4096 * 2;  // 16 MiB
  char* w = (char*)d_ws;
  const int n8_act = 2048 * 4096 / 8;
  const int n8_wt  = 4096 * 4096 / 8;

  if (ws_size >= 13 * SB) {
    ushort* hb  = (ushort*)(w);
    ushort* lb  = (ushort*)(w + 1 * SB);
    ushort* wqb = (ushort*)(w + 2 * SB);   // 2 SB
    ushort* wkv = (ushort*)(w + 4 * SB);   // 4 SB: [Wk;Wv] stacked [8192,4096]
    ushort* wob = (ushort*)(w + 8 * SB);   // 2 SB
    ushort* Qb  = (ushort*)(w + 10 * SB);
    ushort* Kbf = (ushort*)(w + 11 * SB);
    ushort* Vtb = (ushort*)(w + 12 * SB);
    ushort* AOb = wqb;                      // reuse after QKV GEMM
    float*  Pp  = (float*)(w + 4 * SB);     // 64MB partials, reuse wkv region

    cvt_bf16<<<n8_act / 256, 256, 0, stream>>>(hidden,  hb,  n8_act);
    cvt_bf16<<<n8_act / 256, 256, 0, stream>>>(latents, lb,  n8_act);
    cvt_bf16<<<n8_wt / 256, 256, 0, stream>>>(Wq, wqb, n8_wt);
    cvt_bf16<<<n8_wt / 256, 256, 0, stream>>>(Wk, wkv, n8_wt);
    cvt_bf16<<<n8_wt / 256, 256, 0, stream>>>(Wv, wkv + (size_t)4096 * 4096, n8_wt);
    cvt_bf16<<<n8_wt / 256, 256, 0, stream>>>(Wo, wob, n8_wt);

    gemm8<64, 0><<<dim3(384), 512, 0, stream>>>(hb, lb, wkv, wqb, Kbf, Vtb, Qb, nullptr);
    rope_kernel<<<(2048 * 32 * 64) / 256, 256, 0, stream>>>(Kbf);
    flash_attn<<<dim3(16, 32), 512, 0, stream>>>(Qb, Kbf, Vtb, AOb);
    gemm8<32, 1><<<dim3(256), 512, 0, stream>>>(AOb, AOb, wob, wob,
                                                nullptr, nullptr, nullptr, Pp);
    reduce2<<<(2048 * 4096 / 4 + 255) / 256, 256, 0, stream>>>(Pp, out, 2048 * 4096 / 4);
  } else {
    ushort* Qb  = (ushort*)(w);
    ushort* Kbf = (ushort*)(w + 1 * SB);
    ushort* Vtb = (ushort*)(w + 2 * SB);
    ushort* AOb = (ushort*)(w + 3 * SB);

    gemm_bt<false><<<dim3(32, 16), 256, 0, stream>>>(latents, Wq, Qb, 2048, 4096, 4096, 4096);
    gemm_bt<false><<<dim3(32, 16), 256, 0, stream>>>(hidden, Wk, Kbf, 2048, 4096, 4096, 4096);
    gemm_bt<true><<<dim3(32, 16), 256, 0, stream>>>(hidden, Wv, Vtb, 2048, 4096, 4096, 2048);
    rope_kernel<<<(2048 * 32 * 64) / 256, 256, 0, stream>>>(Kbf);
    flash_attn<<<dim3(16, 32), 512, 0, stream>>>(Qb, Kbf, Vtb, AOb);
    gemm_bt<false><<<dim3(32, 16), 256, 0, stream>>>(AOb, Wo, out, 2048, 4096, 4096, 4096);
  }
}

// Round 3
// 809.848 us; speedup vs baseline: 1.2777x; 1.0384x over previous
//
#include <hip/hip_runtime.h>
#include <cstdint>
#include <type_traits>

typedef short bf16x8 __attribute__((ext_vector_type(8)));
typedef float f32x4 __attribute__((ext_vector_type(4)));

__device__ __forceinline__ ushort f2bf(float f) {
  union { float f; uint32_t u; } v; v.f = f;
  return (ushort)((v.u + 0x7fffu + ((v.u >> 16) & 1u)) >> 16);
}
__device__ __forceinline__ float bf2f(ushort u) {
  union { uint32_t u; float f; } v; v.u = ((uint32_t)u) << 16;
  return v.f;
}
__device__ __forceinline__ uint32_t pkbf(float x, float y) {
  uint32_t ux = (__float_as_uint(x) + 0x8000u) >> 16;
  uint32_t uy = (__float_as_uint(y) + 0x8000u) & 0xffff0000u;
  return ux | uy;
}

// async global->LDS, 16B per lane; LDS base must be wave-uniform,
// HW writes lane l at base + l*16.
__device__ __forceinline__ void gld16(const void* g, void* l) {
  __builtin_amdgcn_global_load_lds(
      (__attribute__((address_space(1))) void*)(g),
      (__attribute__((address_space(3))) void*)(l), 16, 0, 0);
}

__device__ __forceinline__ uint4 ld8(const ushort* p) { return *(const uint4*)p; }
__device__ __forceinline__ uint4 ld8(const float* p) {
  float4 a = *(const float4*)p;
  float4 b = *(const float4*)(p + 4);
  uint4 r;
  r.x = pkbf(a.x, a.y); r.y = pkbf(a.z, a.w);
  r.z = pkbf(b.x, b.y); r.w = pkbf(b.z, b.w);
  return r;
}

// ---------------------------------------------------------------------------
// fp32 -> bf16 bulk convert: 8 elements/thread
// ---------------------------------------------------------------------------
__global__ __launch_bounds__(256) void cvt_bf16(
    const float* __restrict__ src, ushort* __restrict__ dst, int n8)
{
  int i = blockIdx.x * 256 + threadIdx.x;
  if (i >= n8) return;
  const float4* s = (const float4*)src;
  float4 a = s[2 * i], b = s[2 * i + 1];
  uint4 r;
  r.x = pkbf(a.x, a.y); r.y = pkbf(a.z, a.w);
  r.z = pkbf(b.x, b.y); r.w = pkbf(b.z, b.w);
  ((uint4*)dst)[i] = r;
}

// ===========================================================================
// 256x256 8-phase GEMM template (m201-style), 512 threads = 8 waves (2Mx4N),
// BK=64, 128 KiB LDS, counted vmcnt(6), setprio, SWIZZLED subtile LDS layout:
//   16B-unit involution u' = u ^ ((u>>3)&3) inside each 1KiB subtile.
//   Write side: linear LDS (global_load_lds) + permuted GLOBAL source c8.
//   Read side: frag offset l16*32 + (quad ^ ((l16>>1)&3))*8.
//   => every 8 consecutive lanes hit 8 distinct bank-groups: 0 conflicts.
// MODE 0: QKV fused (A in {hb,lb}, B in {wkv,wq}; route K / V^T / Q, bf16 out)
// MODE 1: split-K out-GEMM (A=AO, B=Wo; kz selects K-half; fp32 partials)
// NT = number of BK=64 K-tiles.
// ===========================================================================

#define BARw() __builtin_amdgcn_s_barrier()
#define LGKMW() do { asm volatile("s_waitcnt lgkmcnt(0)" ::: "memory"); \
                     __builtin_amdgcn_sched_barrier(0); } while (0)
#define VM6() asm volatile("s_waitcnt vmcnt(6)" ::: "memory")
#define VM0() asm volatile("s_waitcnt vmcnt(0)" ::: "memory")

// Stage one 128x64 half-tile (16 KiB) into LDS (swizzled subtile layout).
// c8s is the pre-swizzled per-lane global column offset.
__device__ __forceinline__ void stage_half8(
    const ushort* __restrict__ G, int row0, int col0,
    ushort* lds, int wave, int r4, int c8s)
{
#pragma unroll
  for (int q = 0; q < 2; ++q) {
    const int si = q * 8 + wave;
    const ushort* g = G + (size_t)(row0 + (si >> 1) * 16 + r4) * 4096
                        + (col0 + (si & 1) * 32 + c8s);
    gld16(g, lds + si * 512);
  }
}

// A-fragment reads: 4 m-frags x 2 k-steps from one half (8 x ds_read_b128).
// qsw = (quad ^ ((l16>>1)&3)) * 8  (swizzled within-row unit).
__device__ __forceinline__ void read_a8(const ushort* base, int wm, int l16,
                                        int qsw, bf16x8 (&a)[4][2])
{
#pragma unroll
  for (int f = 0; f < 4; ++f)
#pragma unroll
    for (int ks = 0; ks < 2; ++ks)
      a[f][ks] = *(const bf16x8*)(base + ((wm * 4 + f) * 2 + ks) * 512
                                       + l16 * 32 + qsw);
}

// B-fragment reads: 2 n-frags x 2 k-steps from one half (4 x ds_read_b128).
__device__ __forceinline__ void read_b8(const ushort* base, int wn, int l16,
                                        int qsw, bf16x8 (&b)[2][2])
{
#pragma unroll
  for (int f = 0; f < 2; ++f)
#pragma unroll
    for (int ks = 0; ks < 2; ++ks)
      b[f][ks] = *(const bf16x8*)(base + ((wn * 2 + f) * 2 + ks) * 512
                                       + l16 * 32 + qsw);
}

template <int MH, int NH>
__device__ __forceinline__ void mfma_quad(const bf16x8 (&a)[4][2],
                                          const bf16x8 (&b)[2][2],
                                          f32x4 (&acc)[8][4])
{
  __builtin_amdgcn_s_setprio(1);
#pragma unroll
  for (int ks = 0; ks < 2; ++ks)
#pragma unroll
    for (int f = 0; f < 4; ++f)
#pragma unroll
      for (int g = 0; g < 2; ++g)
        acc[MH * 4 + f][NH * 2 + g] = __builtin_amdgcn_mfma_f32_16x16x32_bf16(
            a[f][ks], b[g][ks], acc[MH * 4 + f][NH * 2 + g], 0, 0, 0);
  __builtin_amdgcn_s_setprio(0);
}

template <int NT, int MODE>
__global__ __launch_bounds__(512, 2) void gemm8(
    const ushort* __restrict__ A0, const ushort* __restrict__ A1,
    const ushort* __restrict__ B0, const ushort* __restrict__ B1,
    ushort* __restrict__ O0, ushort* __restrict__ O1, ushort* __restrict__ O2,
    float* __restrict__ PF)
{
  // [buf(2)][mat A/B][half(2)][8192 ushorts] = 128 KiB
  __shared__ __align__(16) ushort smem[65536];
#define LDSA(P, H) (smem + (P) * 32768 + (H) * 8192)
#define LDSB(P, H) (smem + (P) * 32768 + 16384 + (H) * 8192)

  const int tid  = threadIdx.x;
  const int wave = tid >> 6;
  const int lane = tid & 63;
  const int quad = lane >> 4;
  const int l16  = lane & 15;
  const int wm   = wave >> 2;        // 0..1
  const int wn   = wave & 3;         // 0..3
  const int r4   = lane >> 2;
  // swizzled staging source column: unit' = lane ^ ((lane>>3)&3) (row-local)
  const int c8s  = (((lane & 3) ^ ((lane >> 3) & 3))) * 8;
  // swizzled fragment read unit within row
  const int qsw  = (quad ^ ((l16 >> 1) & 3)) * 8;

  const int bid = blockIdx.x;
  const ushort* Ag; const ushort* Bg;
  int m0, n0, kbase = 0, route = 0, kz = 0;
  if constexpr (MODE == 0) {
    // 384 blocks, bijective XCD swizzle (48 per XCD chunk)
    const int swz = (bid & 7) * 48 + (bid >> 3);
    const int xt  = swz % 48;
    m0 = (swz / 48) * 256;
    if (xt < 32) { Ag = A0; Bg = B0; n0 = xt * 256; }
    else         { Ag = A1; Bg = B1; n0 = (xt - 32) * 256; }
    route = (xt >= 32) ? 2 : (n0 >= 4096 ? 1 : 0);
  } else {
    // 256 blocks, bijective XCD swizzle (32 per XCD chunk)
    const int swz = (bid & 7) * 32 + (bid >> 3);
    kz = swz >> 7;
    const int r = swz & 127;
    m0 = (r >> 4) * 256;
    n0 = (r & 15) * 256;
    kbase = kz * 2048;
    Ag = A0; Bg = B0;
  }

  f32x4 acc[8][4];
#pragma unroll
  for (int i = 0; i < 8; ++i)
#pragma unroll
    for (int j = 0; j < 4; ++j) acc[i][j] = {0.f, 0.f, 0.f, 0.f};

  bf16x8 a[4][2], b0[2][2], b1[2][2];

  // ---- prologue: tile 0 (4 halves) + tile 1 (3 halves) -------------------
  stage_half8(Ag, m0,       kbase,      LDSA(0, 0), wave, r4, c8s);
  stage_half8(Bg, n0,       kbase,      LDSB(0, 0), wave, r4, c8s);
  stage_half8(Bg, n0 + 128, kbase,      LDSB(0, 1), wave, r4, c8s);
  stage_half8(Ag, m0 + 128, kbase,      LDSA(0, 1), wave, r4, c8s);
  stage_half8(Ag, m0,       kbase + 64, LDSA(1, 0), wave, r4, c8s);
  stage_half8(Bg, n0,       kbase + 64, LDSB(1, 0), wave, r4, c8s);
  stage_half8(Bg, n0 + 128, kbase + 64, LDSB(1, 1), wave, r4, c8s);
  VM6();                 // oldest 8 loads (= tile 0) landed; 3 halves in flight
  BARw();

  // ---- main loop: 2 K-tiles (8 phases) per iteration ---------------------
#pragma unroll 1
  for (int t = 0; t < NT; t += 2) {
    // ======== tile t (buf 0) ========
    read_a8(LDSA(0, 0), wm, l16, qsw, a);
    read_b8(LDSB(0, 0), wn, l16, qsw, b0);
    stage_half8(Ag, m0 + 128, kbase + (t + 1) * 64, LDSA(1, 1), wave, r4, c8s);
    BARw(); LGKMW();
    mfma_quad<0, 0>(a, b0, acc);
    BARw();

    read_b8(LDSB(0, 1), wn, l16, qsw, b1);
    if (t < NT - 2) stage_half8(Ag, m0, kbase + (t + 2) * 64, LDSA(0, 0), wave, r4, c8s);
    BARw(); LGKMW();
    mfma_quad<0, 1>(a, b1, acc);
    BARw();

    read_a8(LDSA(0, 1), wm, l16, qsw, a);
    if (t < NT - 2) stage_half8(Bg, n0, kbase + (t + 2) * 64, LDSB(0, 0), wave, r4, c8s);
    BARw(); LGKMW();
    mfma_quad<1, 0>(a, b0, acc);
    BARw();

    if (t < NT - 2) stage_half8(Bg, n0 + 128, kbase + (t + 2) * 64, LDSB(0, 1), wave, r4, c8s);
    BARw(); LGKMW();
    mfma_quad<1, 1>(a, b1, acc);
    if (t < NT - 2) VM6(); else VM0();
    BARw();

    // ======== tile t+1 (buf 1) ========
    read_a8(LDSA(1, 0), wm, l16, qsw, a);
    read_b8(LDSB(1, 0), wn, l16, qsw, b0);
    if (t < NT - 2) stage_half8(Ag, m0 + 128, kbase + (t + 2) * 64, LDSA(0, 1), wave, r4, c8s);
    BARw(); LGKMW();
    mfma_quad<0, 0>(a, b0, acc);
    BARw();

    read_b8(LDSB(1, 1), wn, l16, qsw, b1);
    if (t < NT - 3) stage_half8(Ag, m0, kbase + (t + 3) * 64, LDSA(1, 0), wave, r4, c8s);
    BARw(); LGKMW();
    mfma_quad<0, 1>(a, b1, acc);
    BARw();

    read_a8(LDSA(1, 1), wm, l16, qsw, a);
    if (t < NT - 3) stage_half8(Bg, n0, kbase + (t + 3) * 64, LDSB(1, 0), wave, r4, c8s);
    BARw(); LGKMW();
    mfma_quad<1, 0>(a, b0, acc);
    BARw();

    if (t < NT - 3) stage_half8(Bg, n0 + 128, kbase + (t + 3) * 64, LDSB(1, 1), wave, r4, c8s);
    BARw(); LGKMW();
    mfma_quad<1, 1>(a, b1, acc);
    if (t < NT - 4) { VM6(); } else if (t < NT - 2) { VM0(); }
    BARw();
  }

  // ---- epilogue ----------------------------------------------------------
  if constexpr (MODE == 0) {
#pragma unroll
    for (int fm = 0; fm < 8; ++fm) {
      const int rowb = m0 + (fm >> 2) * 128 + wm * 64 + (fm & 3) * 16 + quad * 4;
#pragma unroll
      for (int fn = 0; fn < 4; ++fn) {
        const int col = n0 + (fn >> 1) * 128 + wn * 32 + (fn & 1) * 16 + l16;
#pragma unroll
        for (int r = 0; r < 4; ++r) {
          const ushort val = f2bf(acc[fm][fn][r]);
          const int row = rowb + r;
          if (route == 0)      O0[(size_t)row * 4096 + col] = val;
          else if (route == 1) O1[(size_t)(col - 4096) * 2048 + row] = val;
          else                 O2[(size_t)row * 4096 + col] = val;
        }
      }
    }
  } else {
    float* myP = PF + (size_t)kz * 2048 * 4096;
#pragma unroll
    for (int fm = 0; fm < 8; ++fm) {
      const int rowb = m0 + (fm >> 2) * 128 + wm * 64 + (fm & 3) * 16 + quad * 4;
#pragma unroll
      for (int fn = 0; fn < 4; ++fn) {
        const int col = n0 + (fn >> 1) * 128 + wn * 32 + (fn & 1) * 16 + l16;
#pragma unroll
        for (int r = 0; r < 4; ++r)
          myP[(size_t)(rowb + r) * 4096 + col] = acc[fm][fn][r];
      }
    }
  }
#undef LDSA
#undef LDSB
}

__global__ __launch_bounds__(256) void reduce2(
    const float* __restrict__ P, float* __restrict__ out, int n4)
{
  int i = blockIdx.x * 256 + threadIdx.x;
  if (i >= n4) return;
  const float4* p0 = (const float4*)P;
  const float4* p1 = (const float4*)(P + (size_t)2048 * 4096);
  float4 a = p0[i], b = p1[i];
  float4 r; r.x = a.x + b.x; r.y = a.y + b.y; r.z = a.z + b.z; r.w = a.w + b.w;
  ((float4*)out)[i] = r;
}

// ---------------------------------------------------------------------------
// FALLBACK GEMM (mixed fp32/bf16 inputs, VGPR staging)
// ---------------------------------------------------------------------------
template <bool TRANSC, typename TA, typename TB, typename TC>
__global__ __launch_bounds__(256) void gemm_bt(
    const TA* __restrict__ A, const TB* __restrict__ B,
    TC* __restrict__ C, int M, int N, int K, int ldc)
{
  __shared__ __align__(16) ushort As[128 * 32];
  __shared__ __align__(16) ushort Bs[128 * 32];

  const int tid  = threadIdx.x;
  const int wave = tid >> 6;
  const int lane = tid & 63;
  const int quad = lane >> 4;
  const int l16  = lane & 15;
  const int m0 = blockIdx.y * 128;
  const int n0 = blockIdx.x * 128;
  const int wm = (wave & 1) * 64;
  const int wn = (wave >> 1) * 64;
  const int r0 = tid >> 2;
  const int c0 = (tid & 3) * 8;

  f32x4 acc[4][4];
#pragma unroll
  for (int i = 0; i < 4; i++)
#pragma unroll
    for (int j = 0; j < 4; j++) acc[i][j] = {0.f, 0.f, 0.f, 0.f};

  const TA* aptr = A + (size_t)(m0 + r0) * K + c0;
  const TB* bptr = B + (size_t)(n0 + r0) * K + c0;

  for (int k0 = 0; k0 < K; k0 += 32) {
    uint4 av0 = ld8(aptr + k0);
    uint4 av1 = ld8(aptr + (size_t)64 * K + k0);
    uint4 bv0 = ld8(bptr + k0);
    uint4 bv1 = ld8(bptr + (size_t)64 * K + k0);
    __syncthreads();
    *(uint4*)(As + r0 * 32 + c0)        = av0;
    *(uint4*)(As + (r0 + 64) * 32 + c0) = av1;
    *(uint4*)(Bs + r0 * 32 + c0)        = bv0;
    *(uint4*)(Bs + (r0 + 64) * 32 + c0) = bv1;
    __syncthreads();

    bf16x8 af[4], bfr[4];
#pragma unroll
    for (int i = 0; i < 4; i++) {
      af[i]  = *(const bf16x8*)(As + (wm + i * 16 + l16) * 32 + quad * 8);
      bfr[i] = *(const bf16x8*)(Bs + (wn + i * 16 + l16) * 32 + quad * 8);
    }
#pragma unroll
    for (int im = 0; im < 4; im++)
#pragma unroll
      for (int in = 0; in < 4; in++)
        acc[im][in] = __builtin_amdgcn_mfma_f32_16x16x32_bf16(
            af[im], bfr[in], acc[im][in], 0, 0, 0);
  }

#pragma unroll
  for (int im = 0; im < 4; im++)
#pragma unroll
    for (int in = 0; in < 4; in++)
#pragma unroll
      for (int r = 0; r < 4; r++) {
        int row = m0 + wm + im * 16 + quad * 4 + r;
        int col = n0 + wn + in * 16 + l16;
        float fv = acc[im][in][r];
        TC val;
        if constexpr (std::is_same<TC, ushort>::value) val = f2bf(fv);
        else                                           val = fv;
        if (TRANSC) C[(size_t)col * ldc + row] = val;
        else        C[(size_t)row * ldc + col] = val;
      }
}

// ---------------------------------------------------------------------------
// RoPE on K (bf16) in place
// ---------------------------------------------------------------------------
__global__ __launch_bounds__(256) void rope_kernel(ushort* __restrict__ Kb)
{
  int idx = blockIdx.x * 256 + threadIdx.x;
  int j  = idx & 63;
  int hs = idx >> 6;
  int s  = hs >> 5;
  float freq = expf(-0.14391156f * (float)j);
  float ang  = (float)s * freq;
  float sn, c;
  sincosf(ang, &sn, &c);
  size_t base = (size_t)hs * 128 + j;
  float k1 = bf2f(Kb[base]);
  float k2 = bf2f(Kb[base + 64]);
  Kb[base]      = f2bf(k1 * c - k2 * sn);
  Kb[base + 64] = f2bf(k2 * c + k1 * sn);
}

// ---------------------------------------------------------------------------
// Flash attention v2: 512 threads = 8 waves, 1 head x 128 q rows per block,
// 128-key tiles, async-STAGE (T14), setprio (T5), defer-max (T13).
// LDS: K 32K + V 32K + P 32K = 96 KiB. Grid (16, 32).
// ---------------------------------------------------------------------------
__global__ __launch_bounds__(512, 2) void flash_attn(
    const ushort* __restrict__ Q, const ushort* __restrict__ Kb,
    const ushort* __restrict__ Vt, ushort* __restrict__ AO)
{
  __shared__ __align__(16) ushort Kt[128 * 128];
  __shared__ __align__(16) ushort Vs[128 * 128];
  __shared__ __align__(16) ushort Ps[8][16 * 128];

  const int tid  = threadIdx.x;
  const int wave = tid >> 6;
  const int lane = tid & 63;
  const int quad = lane >> 4;
  const int l16  = lane & 15;
  const int h  = blockIdx.y;
  const int q0 = blockIdx.x * 128 + wave * 16;
  const float scale = 0.08838834764831845f;

  bf16x8 aq[4];
#pragma unroll
  for (int kt = 0; kt < 4; kt++)
    aq[kt] = *(const bf16x8*)(Q + (size_t)(q0 + l16) * 4096 + h * 128 + kt * 32 + quad * 8);

  f32x4 Oacc[8];
#pragma unroll
  for (int dt = 0; dt < 8; dt++) Oacc[dt] = {0.f, 0.f, 0.f, 0.f};
  float m_i[4], l_i[4];
#pragma unroll
  for (int r = 0; r < 4; r++) { m_i[r] = -1e30f; l_i[r] = 0.f; }

  ushort* myP = &Ps[wave][0];

  // T14: prefetch registers for next K/V tile (4 x 16B each)
  uint4 kr[4], vr[4];
#pragma unroll
  for (int it = 0; it < 4; ++it) {
    int i = tid + it * 512;
    int row = i >> 4, g = i & 15;
    kr[it] = *(const uint4*)(Kb + (size_t)row * 4096 + h * 128 + g * 8);
    vr[it] = *(const uint4*)(Vt + (size_t)(h * 128 + row) * 2048 + g * 8);
  }

  for (int kv = 0; kv < 2048; kv += 128) {
    __syncthreads();   // previous compute done reading LDS
#pragma unroll
    for (int it = 0; it < 4; ++it) {
      int i = tid + it * 512;
      int row = i >> 4, g = i & 15;
      int sw = (g ^ (row & 15)) * 8;
      *(uint4*)(Kt + row * 128 + sw) = kr[it];
      *(uint4*)(Vs + row * 128 + sw) = vr[it];
    }
    __syncthreads();

    // issue next tile's global loads early; they complete during compute
    if (kv + 128 < 2048) {
#pragma unroll
      for (int it = 0; it < 4; ++it) {
        int i = tid + it * 512;
        int row = i >> 4, g = i & 15;
        kr[it] = *(const uint4*)(Kb + (size_t)(kv + 128 + row) * 4096 + h * 128 + g * 8);
        vr[it] = *(const uint4*)(Vt + (size_t)(h * 128 + row) * 2048 + kv + 128 + g * 8);
      }
    }

    // ---- QK^T -----------------------------------------------------------
    f32x4 sA[8];
#pragma unroll
    for (int nt = 0; nt < 8; nt++) sA[nt] = {0.f, 0.f, 0.f, 0.f};
    __builtin_amdgcn_s_setprio(1);
#pragma unroll
    for (int nt = 0; nt < 8; nt++) {
      int row = nt * 16 + l16;
#pragma unroll
      for (int kt = 0; kt < 4; kt++) {
        int g = kt * 4 + quad;
        bf16x8 bk = *(const bf16x8*)(Kt + row * 128 + ((g ^ (row & 15)) * 8));
        sA[nt] = __builtin_amdgcn_mfma_f32_16x16x32_bf16(aq[kt], bk, sA[nt], 0, 0, 0);
      }
    }
    __builtin_amdgcn_s_setprio(0);

    // ---- online softmax with defer-max (T13, THR=8) ---------------------
    float tmax[4];
#pragma unroll
    for (int r = 0; r < 4; r++) {
      float m = sA[0][r];
#pragma unroll
      for (int nt = 1; nt < 8; nt++) m = fmaxf(m, sA[nt][r]);
      tmax[r] = m;
    }
#pragma unroll
    for (int msk = 1; msk < 16; msk <<= 1)
#pragma unroll
      for (int r = 0; r < 4; r++)
        tmax[r] = fmaxf(tmax[r], __shfl_xor(tmax[r], msk));

    float nm[4];
    float growth = -1e30f;
#pragma unroll
    for (int r = 0; r < 4; r++) {
      nm[r] = tmax[r] * scale;
      growth = fmaxf(growth, nm[r] - m_i[r]);
    }
    if (__any(growth > 8.0f)) {
#pragma unroll
      for (int r = 0; r < 4; r++) {
        float mn = fmaxf(m_i[r], nm[r]);
        float al = __expf(m_i[r] - mn);
        m_i[r] = mn;
        l_i[r] *= al;
#pragma unroll
        for (int dt = 0; dt < 8; dt++) Oacc[dt][r] *= al;
      }
    }

    float rsum[4] = {0.f, 0.f, 0.f, 0.f};
#pragma unroll
    for (int nt = 0; nt < 8; nt++)
#pragma unroll
      for (int r = 0; r < 4; r++) {
        float p = __expf(sA[nt][r] * scale - m_i[r]);
        sA[nt][r] = p;
        rsum[r] += p;
      }
#pragma unroll
    for (int msk = 1; msk < 16; msk <<= 1)
#pragma unroll
      for (int r = 0; r < 4; r++) rsum[r] += __shfl_xor(rsum[r], msk);
#pragma unroll
    for (int r = 0; r < 4; r++) l_i[r] += rsum[r];

    // ---- P -> LDS (swizzled) --------------------------------------------
#pragma unroll
    for (int nt = 0; nt < 8; nt++)
#pragma unroll
      for (int r = 0; r < 4; r++) {
        int row = quad * 4 + r;
        int col = nt * 16 + l16;
        myP[row * 128 + (((col >> 3) ^ row) * 8) + (col & 7)] = f2bf(sA[nt][r]);
      }

    // ---- PV ---------------------------------------------------------------
    __builtin_amdgcn_s_setprio(1);
#pragma unroll
    for (int kt = 0; kt < 4; kt++) {
      int g = kt * 4 + quad;
      bf16x8 ap = *(const bf16x8*)(myP + l16 * 128 + ((g ^ l16) * 8));
#pragma unroll
      for (int dt = 0; dt < 8; dt++) {
        int vrow = dt * 16 + l16;
        bf16x8 bv = *(const bf16x8*)(Vs + vrow * 128 + ((g ^ (vrow & 15)) * 8));
        Oacc[dt] = __builtin_amdgcn_mfma_f32_16x16x32_bf16(ap, bv, Oacc[dt], 0, 0, 0);
      }
    }
    __builtin_amdgcn_s_setprio(0);
  }

#pragma unroll
  for (int dt = 0; dt < 8; dt++)
#pragma unroll
    for (int r = 0; r < 4; r++) {
      int row = q0 + quad * 4 + r;
      int col = h * 128 + dt * 16 + l16;
      AO[(size_t)row * 4096 + col] = f2bf(Oacc[dt][r] / l_i[r]);
    }
}

// ---------------------------------------------------------------------------
extern "C" void kernel_launch(void* const* d_in, const int* in_sizes, int n_in,
                              void* d_out, int out_size, void* d_ws, size_t ws_size,
                              hipStream_t stream)
{
  const float* hidden  = (const float*)d_in[0];
  const float* Wq      = (const float*)d_in[2];
  const float* Wk      = (const float*)d_in[3];
  const float* Wv      = (const float*)d_in[4];
  const float* Wo      = (const float*)d_in[5];
  const float* latents = (const float*)d_in[6];
  float* out = (float*)d_out;

  const size_t SB = (size_t)2048 * 4096 * 2;  // 16 MiB
  char* w = (char*)d_ws;
  const int n8_act = 2048 * 4096 / 8;
  const int n8_wt  = 4096 * 4096 / 8;

  if (ws_size >= 13 * SB) {
    ushort* hb  = (ushort*)(w);
    ushort* lb  = (ushort*)(w + 1 * SB);
    ushort* wqb = (ushort*)(w + 2 * SB);   // 2 SB
    ushort* wkv = (ushort*)(w + 4 * SB);   // 4 SB: [Wk;Wv] stacked [8192,4096]
    ushort* wob = (ushort*)(w + 8 * SB);   // 2 SB
    ushort* Qb  = (ushort*)(w + 10 * SB);
    ushort* Kbf = (ushort*)(w + 11 * SB);
    ushort* Vtb = (ushort*)(w + 12 * SB);
    ushort* AOb = wqb;                      // reuse after QKV GEMM
    float*  Pp  = (float*)(w + 4 * SB);     // 64MB partials, reuse wkv region

    cvt_bf16<<<n8_act / 256, 256, 0, stream>>>(hidden,  hb,  n8_act);
    cvt_bf16<<<n8_act / 256, 256, 0, stream>>>(latents, lb,  n8_act);
    cvt_bf16<<<n8_wt / 256, 256, 0, stream>>>(Wq, wqb, n8_wt);
    cvt_bf16<<<n8_wt / 256, 256, 0, stream>>>(Wk, wkv, n8_wt);
    cvt_bf16<<<n8_wt / 256, 256, 0, stream>>>(Wv, wkv + (size_t)4096 * 4096, n8_wt);
    cvt_bf16<<<n8_wt / 256, 256, 0, stream>>>(Wo, wob, n8_wt);

    gemm8<64, 0><<<dim3(384), 512, 0, stream>>>(hb, lb, wkv, wqb, Kbf, Vtb, Qb, nullptr);
    rope_kernel<<<(2048 * 32 * 64) / 256, 256, 0, stream>>>(Kbf);
    flash_attn<<<dim3(16, 32), 512, 0, stream>>>(Qb, Kbf, Vtb, AOb);
    gemm8<32, 1><<<dim3(256), 512, 0, stream>>>(AOb, AOb, wob, wob,
                                                nullptr, nullptr, nullptr, Pp);
    reduce2<<<(2048 * 4096 / 4 + 255) / 256, 256, 0, stream>>>(Pp, out, 2048 * 4096 / 4);
  } else {
    ushort* Qb  = (ushort*)(w);
    ushort* Kbf = (ushort*)(w + 1 * SB);
    ushort* Vtb = (ushort*)(w + 2 * SB);
    ushort* AOb = (ushort*)(w + 3 * SB);

    gemm_bt<false><<<dim3(32, 16), 256, 0, stream>>>(latents, Wq, Qb, 2048, 4096, 4096, 4096);
    gemm_bt<false><<<dim3(32, 16), 256, 0, stream>>>(hidden, Wk, Kbf, 2048, 4096, 4096, 4096);
    gemm_bt<true><<<dim3(32, 16), 256, 0, stream>>>(hidden, Wv, Vtb, 2048, 4096, 4096, 2048);
    rope_kernel<<<(2048 * 32 * 64) / 256, 256, 0, stream>>>(Kbf);
    flash_attn<<<dim3(16, 32), 512, 0, stream>>>(Qb, Kbf, Vtb, AOb);
    gemm_bt<false><<<dim3(32, 16), 256, 0, stream>>>(AOb, Wo, out, 2048, 4096, 4096, 4096);
  }
}